// Round 6
// baseline (556.836 us; speedup 1.0000x reference)
//
#include <hip/hip_runtime.h>

typedef short short8 __attribute__((ext_vector_type(8)));
typedef float f32x4 __attribute__((ext_vector_type(4)));

#define DIMS   256
#define KCODES 8192
#define NTOK   32768
#define BM     64
#define BN     64
#define NTILES 128
#define MARGIN 0.75f    // ~18 sigma of bf16 score error (sigma ~0.04)
#define CAP    3072     // 48 candidates/token

__device__ __forceinline__ unsigned short f2bf(float f) {
    unsigned u = __builtin_bit_cast(unsigned, f);
    unsigned r = (u + 0x7FFFu + ((u >> 16) & 1u)) >> 16;   // RNE
    return (unsigned short)r;
}
__device__ __forceinline__ unsigned fenc(float f) {        // order-preserving float->uint (cold path)
    unsigned u = __builtin_bit_cast(unsigned, f);
    return ((int)u >= 0) ? (u | 0x80000000u) : ~u;
}
// async 16B global->LDS (dest linear: wave-uniform base + lane*16)
__device__ __forceinline__ void gload_lds16(const void* g, void* l) {
    __builtin_amdgcn_global_load_lds(
        (const __attribute__((address_space(1))) unsigned*)g,
        (__attribute__((address_space(3))) unsigned*)l, 16, 0, 0);
}

// fused: c2[k] = ||cb[k]||^2 (fp32) and optional fp32->bf16 codebook convert.
__global__ __launch_bounds__(256) void prep_kernel(const float* __restrict__ cb,
                                                   float* __restrict__ c2,
                                                   unsigned short* __restrict__ cbbf,
                                                   int do_conv) {
    int row  = blockIdx.x * 4 + (threadIdx.x >> 6);
    int lane = threadIdx.x & 63;
    float4 v = *(const float4*)(cb + (size_t)row * DIMS + (size_t)lane * 4);
    if (do_conv) {
        ushort4 s;
        s.x = f2bf(v.x); s.y = f2bf(v.y); s.z = f2bf(v.z); s.w = f2bf(v.w);
        *(ushort4*)(cbbf + (size_t)row * DIMS + (size_t)lane * 4) = s;
    }
    float s = v.x * v.x + v.y * v.y + v.z * v.z + v.w * v.w;
#pragma unroll
    for (int off = 32; off > 0; off >>= 1) s += __shfl_down(s, off);
    if (lane == 0) c2[row] = s;
}

template <bool WSBF>
__global__ __launch_bounds__(512, 2) void vq_main(const float* __restrict__ h,
                                                  const float* __restrict__ cb,
                                                  const unsigned short* __restrict__ cbbf,
                                                  const float* __restrict__ c2g,
                                                  float* __restrict__ out_q,
                                                  float* __restrict__ out_idx) {
    // double-buffered 64x256 bf16 tile; LDS chunk (row,lc) holds global chunk (row, lc^(row&7))
    __shared__ __align__(16) unsigned short Bs[2][BN * DIMS];   // 65536 B
    __shared__ unsigned mrun[BM];                               // raw float bits (positive) running min
    __shared__ unsigned list[CAP];                              // 12288 B
    __shared__ int cnt;

    const int tid  = threadIdx.x;          // 0..511
    const int lane = tid & 63;
    const int wave = tid >> 6;             // 0..7
    const int l15  = lane & 15;
    const int quad = lane >> 4;
    const int wm   = wave >> 2;            // 0..1 : 32-token group
    const int wn   = wave & 3;             // 0..3 : 16-code stripe
    const int tokBase = blockIdx.x * BM;

    if (tid < BM) mrun[tid] = 0x7F7FFFFFu;   // +3.4e38
    if (tid == 0) cnt = 0;

    // ---- staging geometry ----
    // WSBF: 32KB tile = 2048 x 16B chunks; chunk C = n*512 + tid (n=0..3), dest linear at C*16.
    //       row = C>>5 = n*16 + (tid>>5); src col = (tid&31) ^ (row&7)  ((n*16)&7 == 0)
    const int srow0 = tid >> 5;
    const int scol  = (tid & 31) ^ (srow0 & 7);
    const int srcoff = srow0 * (DIMS * 2) + scol * 16;            // n adds 8192 B
    // fallback (!WSBF): reg-staged, same layout
    short8 g[4];

    auto stage = [&](int t, int buf) {
        if constexpr (WSBF) {
            const char* base = (const char*)cbbf + (size_t)t * (BN * DIMS * 2) + srcoff;
            unsigned short* l0 = &Bs[buf][wave * 512];            // +4096 elems (8KB) per n
#pragma unroll
            for (int n = 0; n < 4; n++)
                gload_lds16(base + n * 8192, l0 + n * 4096);
        } else {
#pragma unroll
            for (int n = 0; n < 4; n++) {
                const size_t off = (size_t)(t * BN + srow0 + n * 16) * DIMS + (tid & 31) * 8;
                float4 v0 = *(const float4*)(cb + off);
                float4 v1 = *(const float4*)(cb + off + 4);
                short8 s;
                s[0] = f2bf(v0.x); s[1] = f2bf(v0.y); s[2] = f2bf(v0.z); s[3] = f2bf(v0.w);
                s[4] = f2bf(v1.x); s[5] = f2bf(v1.y); s[6] = f2bf(v1.z); s[7] = f2bf(v1.w);
                g[n] = s;
            }
        }
    };
    auto stage_write_fb = [&](int buf) {   // only for !WSBF
#pragma unroll
        for (int n = 0; n < 4; n++)
            *(short8*)&Bs[buf][(srow0 + n * 16) * DIMS + scol * 8] = g[n];
    };

    stage(0, 0);   // async (WSBF); latency hides under afr conversion

    // ---- token fragments: wave's 32 tokens x 256 dims (bf16), B-operand layout ----
    short8 afr[2][8];
#pragma unroll
    for (int i = 0; i < 2; i++) {
        const float* base = h + (size_t)(tokBase + wm * 32 + i * 16 + l15) * DIMS + quad * 8;
#pragma unroll
        for (int kk = 0; kk < 8; kk++) {
            float4 v0 = *(const float4*)(base + kk * 32);
            float4 v1 = *(const float4*)(base + kk * 32 + 4);
            short8 s;
            s[0] = f2bf(v0.x); s[1] = f2bf(v0.y); s[2] = f2bf(v0.z); s[3] = f2bf(v0.w);
            s[4] = f2bf(v1.x); s[5] = f2bf(v1.y); s[6] = f2bf(v1.z); s[7] = f2bf(v1.w);
            afr[i][kk] = s;
        }
    }
    if constexpr (!WSBF) stage_write_fb(0);

    // ---- code read geometry under the swizzle (A-operand row = wn*16+l15) ----
    const int bswz = l15 & 7;                    // row&7
    const int bq   = (quad ^ (bswz & 3)) << 3;   // elem offset
    const int bx4  = (bswz & 4) << 3;            // XOR against kk*32

    // ---- main loop: 128 tiles + redo of tile 0; ONE barrier per tile ----
#pragma unroll 1
    for (int it = 0; it <= NTILES; ++it) {
        const int t = (it == NTILES) ? 0 : it;
        __syncthreads();   // staged buf[it&1] complete (barrier drains vmcnt); mrun of tiles < it visible
        const int cur = it & 1;
        if (it < NTILES) stage((it + 1 == NTILES) ? 0 : it + 1, cur ^ 1);

        const bool haveThr = (it > 0);
        float thr0 = 0.f, thr1 = 0.f;
        if (haveThr) {
            thr0 = __builtin_bit_cast(float, mrun[wm * 32 + l15]) + MARGIN;
            thr1 = __builtin_bit_cast(float, mrun[wm * 32 + 16 + l15]) + MARGIN;
        }
        const int cbase = t * BN + wn * 16;
        const float4 cc = *(const float4*)(c2g + cbase + quad * 4);

        const unsigned short* bp = &Bs[cur][(wn * 16 + l15) * DIMS + bq];

        f32x4 acc[2][2];
        acc[0][0] = (f32x4){0,0,0,0}; acc[0][1] = (f32x4){0,0,0,0};
        acc[1][0] = (f32x4){0,0,0,0}; acc[1][1] = (f32x4){0,0,0,0};

        __builtin_amdgcn_s_setprio(1);
#pragma unroll
        for (int kk = 0; kk < 4; kk++) {   // split-K: 4 independent 4-deep chains, 2 MFMA per B-read
            short8 b0 = *(const short8*)(bp + ((kk * 32) ^ bx4));
            short8 b1 = *(const short8*)(bp + (((kk + 4) * 32) ^ bx4));
            acc[0][0] = __builtin_amdgcn_mfma_f32_16x16x32_bf16(b0, afr[0][kk],     acc[0][0], 0, 0, 0);
            acc[1][0] = __builtin_amdgcn_mfma_f32_16x16x32_bf16(b0, afr[1][kk],     acc[1][0], 0, 0, 0);
            acc[0][1] = __builtin_amdgcn_mfma_f32_16x16x32_bf16(b1, afr[0][kk + 4], acc[0][1], 0, 0, 0);
            acc[1][1] = __builtin_amdgcn_mfma_f32_16x16x32_bf16(b1, afr[1][kk + 4], acc[1][1], 0, 0, 0);
        }
        __builtin_amdgcn_s_setprio(0);

        if constexpr (!WSBF) { if (it < NTILES) stage_write_fb(cur ^ 1); }

        // scores: frag i's token = wm*32 + i*16 + l15; codes = cbase + quad*4 + {0..3}
        const int code00 = cbase + quad * 4;
#pragma unroll
        for (int i = 0; i < 2; i++) {
            const int tok = wm * 32 + i * 16 + l15;
            const float th = i ? thr1 : thr0;
            float s0 = fmaf(-2.f, acc[i][0][0], fmaf(-2.f, acc[i][1][0], cc.x));
            float s1 = fmaf(-2.f, acc[i][0][1], fmaf(-2.f, acc[i][1][1], cc.y));
            float s2 = fmaf(-2.f, acc[i][0][2], fmaf(-2.f, acc[i][1][2], cc.z));
            float s3 = fmaf(-2.f, acc[i][0][3], fmaf(-2.f, acc[i][1][3], cc.w));
            float vm = fminf(fminf(s0, s1), fminf(s2, s3));
            if (haveThr) {
                const unsigned tk = (unsigned)(tok << 13);
                if (s0 <= th) { int p = atomicAdd(&cnt, 1); if (p < CAP) list[p] = tk | (unsigned)(code00 + 0); }
                if (s1 <= th) { int p = atomicAdd(&cnt, 1); if (p < CAP) list[p] = tk | (unsigned)(code00 + 1); }
                if (s2 <= th) { int p = atomicAdd(&cnt, 1); if (p < CAP) list[p] = tk | (unsigned)(code00 + 2); }
                if (s3 <= th) { int p = atomicAdd(&cnt, 1); if (p < CAP) list[p] = tk | (unsigned)(code00 + 3); }
            }
            if (it < NTILES) {
                vm = fminf(vm, __shfl_xor(vm, 16));
                vm = fminf(vm, __shfl_xor(vm, 32));
                // positive floats: raw bits are order-preserving for atomicMin; a (theoretical)
                // negative score maps to a huge uint -> mrun stays loose -> only extra emissions.
                if (quad == 0) atomicMin(&mrun[tok], __builtin_bit_cast(unsigned, vm));
            }
        }
    }
    __syncthreads();   // list/cnt final; Bs free for overlay

    // ---- exact fp32 rescore of candidates (best64 overlays Bs) ----
    unsigned long long* best64 = (unsigned long long*)&Bs[0][0];
    if (tid < BM) best64[tid] = ~0ULL;
    __syncthreads();

    int n = cnt; if (n > CAP) n = CAP;
    for (int p = wave; p < n; p += 8) {
        unsigned e = list[p];
        int tok = (int)(e >> 13), code = (int)(e & 8191);
        float4 hv = *(const float4*)(h + (size_t)(tokBase + tok) * DIMS + lane * 4);
        float4 cv = *(const float4*)(cb + (size_t)code * DIMS + lane * 4);
        float d = hv.x * cv.x + hv.y * cv.y + hv.z * cv.z + hv.w * cv.w;
#pragma unroll
        for (int m = 1; m < 64; m <<= 1) d += __shfl_xor(d, m);
        float s = c2g[code] - 2.f * d;
        if (lane == 0)
            atomicMin(&best64[tok], ((unsigned long long)fenc(s) << 32) | (unsigned)code);
    }
    __syncthreads();

    if (tid < BM)
        out_idx[tokBase + tid] = (float)(unsigned)(best64[tid] & 0xFFFFFFFFULL);
#pragma unroll
    for (int e = tid; e < BM * (DIMS / 4); e += 512) {
        int r = e >> 6, c4 = e & 63;
        int idx = (int)(unsigned)(best64[r] & 0xFFFFFFFFULL);
        float4 v = *(const float4*)(cb + (size_t)idx * DIMS + c4 * 4);
        *(float4*)(out_q + (size_t)(tokBase + r) * DIMS + c4 * 4) = v;
    }
}

extern "C" void kernel_launch(void* const* d_in, const int* in_sizes, int n_in,
                              void* d_out, int out_size, void* d_ws, size_t ws_size,
                              hipStream_t stream) {
    const float* h  = (const float*)d_in[0];   // [32768, 256]
    const float* cb = (const float*)d_in[1];   // [8192, 256]
    float* out_q   = (float*)d_out;
    float* out_idx = (float*)d_out + (size_t)NTOK * DIMS;

    float* c2 = (float*)d_ws;                                       // 32 KB
    unsigned short* cbbf = (unsigned short*)((char*)d_ws + 32768);  // 4 MB
    const size_t needed = 32768 + (size_t)KCODES * DIMS * 2;
    const int wsbf = (ws_size >= needed) ? 1 : 0;

    prep_kernel<<<KCODES / 4, 256, 0, stream>>>(cb, c2, cbbf, wsbf);
    if (wsbf)
        vq_main<true><<<NTOK / BM, 512, 0, stream>>>(h, cb, cbbf, c2, out_q, out_idx);
    else
        vq_main<false><<<NTOK / BM, 512, 0, stream>>>(h, cb, (const unsigned short*)nullptr, c2, out_q, out_idx);
}

// Round 7
// 354.796 us; speedup vs baseline: 1.5695x; 1.5695x over previous
//
#include <hip/hip_runtime.h>

typedef short short8 __attribute__((ext_vector_type(8)));
typedef float f32x4 __attribute__((ext_vector_type(4)));

#define DIMS   256
#define KCODES 8192
#define NTOK   32768
#define BM     64
#define BN     64
#define NTILES 128
#define MARGIN 0.75f    // ~18 sigma of bf16 score error (sigma ~0.04)
#define CAP    3072     // 48 candidates/token

__device__ __forceinline__ unsigned short f2bf(float f) {
    unsigned u = __builtin_bit_cast(unsigned, f);
    unsigned r = (u + 0x7FFFu + ((u >> 16) & 1u)) >> 16;   // RNE
    return (unsigned short)r;
}
__device__ __forceinline__ unsigned fenc(float f) {        // order-preserving float->uint (cold path)
    unsigned u = __builtin_bit_cast(unsigned, f);
    return ((int)u >= 0) ? (u | 0x80000000u) : ~u;
}
// async 16B global->LDS (dest linear: wave-uniform base + lane*16)
__device__ __forceinline__ void gload_lds16(const void* g, void* l) {
    __builtin_amdgcn_global_load_lds(
        (const __attribute__((address_space(1))) unsigned*)g,
        (__attribute__((address_space(3))) unsigned*)l, 16, 0, 0);
}

// fused: c2[k] = ||cb[k]||^2 (fp32) and optional fp32->bf16 codebook convert.
__global__ __launch_bounds__(256) void prep_kernel(const float* __restrict__ cb,
                                                   float* __restrict__ c2,
                                                   unsigned short* __restrict__ cbbf,
                                                   int do_conv) {
    int row  = blockIdx.x * 4 + (threadIdx.x >> 6);
    int lane = threadIdx.x & 63;
    float4 v = *(const float4*)(cb + (size_t)row * DIMS + (size_t)lane * 4);
    if (do_conv) {
        ushort4 s;
        s.x = f2bf(v.x); s.y = f2bf(v.y); s.z = f2bf(v.z); s.w = f2bf(v.w);
        *(ushort4*)(cbbf + (size_t)row * DIMS + (size_t)lane * 4) = s;
    }
    float s = v.x * v.x + v.y * v.y + v.z * v.z + v.w * v.w;
#pragma unroll
    for (int off = 32; off > 0; off >>= 1) s += __shfl_down(s, off);
    if (lane == 0) c2[row] = s;
}

template <bool WSBF>
__global__ __launch_bounds__(512, 4) void vq_main(const float* __restrict__ h,
                                                  const float* __restrict__ cb,
                                                  const unsigned short* __restrict__ cbbf,
                                                  const float* __restrict__ c2g,
                                                  float* __restrict__ out_q,
                                                  float* __restrict__ out_idx) {
    // double-buffered 64x256 bf16 tile; LDS chunk (row,lc) holds global chunk (row, lc^(row&7))
    __shared__ __align__(16) unsigned short Bs[2][BN * DIMS];   // 65536 B
    __shared__ unsigned mrun[BM];                               // raw float bits (positive) running min
    __shared__ unsigned list[CAP];                              // 12288 B
    __shared__ int cnt;

    const int tid  = threadIdx.x;          // 0..511
    const int lane = tid & 63;
    const int wave = tid >> 6;             // 0..7
    const int l15  = lane & 15;
    const int quad = lane >> 4;
    const int wm   = wave >> 2;            // 0..1 : 32-token group
    const int wn   = wave & 3;             // 0..3 : 16-code stripe
    const int tokBase = blockIdx.x * BM;

    if (tid < BM) mrun[tid] = 0x7F7FFFFFu;   // +3.4e38
    if (tid == 0) cnt = 0;

    // ---- staging geometry ----
    // WSBF: 32KB tile = 2048 x 16B chunks; chunk C = n*512 + tid (n=0..3), dest linear at C*16.
    //       row = C>>5 = n*16 + (tid>>5); src col = (tid&31) ^ (row&7)  ((n*16)&7 == 0)
    const int srow0 = tid >> 5;
    const int scol  = (tid & 31) ^ (srow0 & 7);
    const int srcoff = srow0 * (DIMS * 2) + scol * 16;            // n adds 8192 B
    // fallback (!WSBF): reg-staged, same layout
    short8 g[4];

    auto stage = [&](int t, int buf) {
        if constexpr (WSBF) {
            const char* base = (const char*)cbbf + (size_t)t * (BN * DIMS * 2) + srcoff;
            unsigned short* l0 = &Bs[buf][wave * 512];            // +4096 elems (8KB) per n
#pragma unroll
            for (int n = 0; n < 4; n++)
                gload_lds16(base + n * 8192, l0 + n * 4096);
        } else {
#pragma unroll
            for (int n = 0; n < 4; n++) {
                const size_t off = (size_t)(t * BN + srow0 + n * 16) * DIMS + (tid & 31) * 8;
                float4 v0 = *(const float4*)(cb + off);
                float4 v1 = *(const float4*)(cb + off + 4);
                short8 s;
                s[0] = f2bf(v0.x); s[1] = f2bf(v0.y); s[2] = f2bf(v0.z); s[3] = f2bf(v0.w);
                s[4] = f2bf(v1.x); s[5] = f2bf(v1.y); s[6] = f2bf(v1.z); s[7] = f2bf(v1.w);
                g[n] = s;
            }
        }
    };
    auto stage_write_fb = [&](int buf) {   // only for !WSBF
#pragma unroll
        for (int n = 0; n < 4; n++)
            *(short8*)&Bs[buf][(srow0 + n * 16) * DIMS + scol * 8] = g[n];
    };

    stage(0, 0);   // async (WSBF); latency hides under afr conversion

    // ---- token fragments: wave's 32 tokens x 256 dims (bf16), B-operand layout ----
    short8 afr[2][8];
#pragma unroll
    for (int i = 0; i < 2; i++) {
        const float* base = h + (size_t)(tokBase + wm * 32 + i * 16 + l15) * DIMS + quad * 8;
#pragma unroll
        for (int kk = 0; kk < 8; kk++) {
            float4 v0 = *(const float4*)(base + kk * 32);
            float4 v1 = *(const float4*)(base + kk * 32 + 4);
            short8 s;
            s[0] = f2bf(v0.x); s[1] = f2bf(v0.y); s[2] = f2bf(v0.z); s[3] = f2bf(v0.w);
            s[4] = f2bf(v1.x); s[5] = f2bf(v1.y); s[6] = f2bf(v1.z); s[7] = f2bf(v1.w);
            afr[i][kk] = s;
        }
    }
    if constexpr (!WSBF) stage_write_fb(0);

    // ---- code read geometry under the swizzle (A-operand row = wn*16+l15) ----
    const int bswz = l15 & 7;                    // row&7
    const int bq   = (quad ^ (bswz & 3)) << 3;   // elem offset
    const int bx4  = (bswz & 4) << 3;            // XOR against kk*32

    // ---- main loop: 128 tiles + redo of tile 0; ONE barrier per tile ----
#pragma unroll 1
    for (int it = 0; it <= NTILES; ++it) {
        const int t = (it == NTILES) ? 0 : it;
        __syncthreads();   // staged buf[it&1] complete (barrier drains vmcnt); mrun of tiles < it visible
        const int cur = it & 1;
        if (it < NTILES) stage((it + 1 == NTILES) ? 0 : it + 1, cur ^ 1);

        const bool haveThr = (it > 0);
        float thr0 = 0.f, thr1 = 0.f;
        if (haveThr) {
            thr0 = __builtin_bit_cast(float, mrun[wm * 32 + l15]) + MARGIN;
            thr1 = __builtin_bit_cast(float, mrun[wm * 32 + 16 + l15]) + MARGIN;
        }
        const int cbase = t * BN + wn * 16;
        const float4 cc = *(const float4*)(c2g + cbase + quad * 4);

        const unsigned short* bp = &Bs[cur][(wn * 16 + l15) * DIMS + bq];

        f32x4 acc[2][2];
        acc[0][0] = (f32x4){0,0,0,0}; acc[0][1] = (f32x4){0,0,0,0};
        acc[1][0] = (f32x4){0,0,0,0}; acc[1][1] = (f32x4){0,0,0,0};

        __builtin_amdgcn_s_setprio(1);
#pragma unroll
        for (int kk = 0; kk < 4; kk++) {   // split-K: 4 independent 4-deep chains, 2 MFMA per B-read
            short8 b0 = *(const short8*)(bp + ((kk * 32) ^ bx4));
            short8 b1 = *(const short8*)(bp + (((kk + 4) * 32) ^ bx4));
            acc[0][0] = __builtin_amdgcn_mfma_f32_16x16x32_bf16(b0, afr[0][kk],     acc[0][0], 0, 0, 0);
            acc[1][0] = __builtin_amdgcn_mfma_f32_16x16x32_bf16(b0, afr[1][kk],     acc[1][0], 0, 0, 0);
            acc[0][1] = __builtin_amdgcn_mfma_f32_16x16x32_bf16(b1, afr[0][kk + 4], acc[0][1], 0, 0, 0);
            acc[1][1] = __builtin_amdgcn_mfma_f32_16x16x32_bf16(b1, afr[1][kk + 4], acc[1][1], 0, 0, 0);
        }
        __builtin_amdgcn_s_setprio(0);

        if constexpr (!WSBF) { if (it < NTILES) stage_write_fb(cur ^ 1); }

        // scores: frag i's token = wm*32 + i*16 + l15; codes = cbase + quad*4 + {0..3}
        const int code00 = cbase + quad * 4;
#pragma unroll
        for (int i = 0; i < 2; i++) {
            const int tok = wm * 32 + i * 16 + l15;
            const float th = i ? thr1 : thr0;
            float s0 = fmaf(-2.f, acc[i][0][0], fmaf(-2.f, acc[i][1][0], cc.x));
            float s1 = fmaf(-2.f, acc[i][0][1], fmaf(-2.f, acc[i][1][1], cc.y));
            float s2 = fmaf(-2.f, acc[i][0][2], fmaf(-2.f, acc[i][1][2], cc.z));
            float s3 = fmaf(-2.f, acc[i][0][3], fmaf(-2.f, acc[i][1][3], cc.w));
            float vm = fminf(fminf(s0, s1), fminf(s2, s3));
            if (haveThr) {
                const unsigned tk = (unsigned)(tok << 13);
                if (s0 <= th) { int p = atomicAdd(&cnt, 1); if (p < CAP) list[p] = tk | (unsigned)(code00 + 0); }
                if (s1 <= th) { int p = atomicAdd(&cnt, 1); if (p < CAP) list[p] = tk | (unsigned)(code00 + 1); }
                if (s2 <= th) { int p = atomicAdd(&cnt, 1); if (p < CAP) list[p] = tk | (unsigned)(code00 + 2); }
                if (s3 <= th) { int p = atomicAdd(&cnt, 1); if (p < CAP) list[p] = tk | (unsigned)(code00 + 3); }
            }
            if (it < NTILES) {
                vm = fminf(vm, __shfl_xor(vm, 16));
                vm = fminf(vm, __shfl_xor(vm, 32));
                // positive floats: raw bits are order-preserving for atomicMin; a (theoretical)
                // negative score maps to a huge uint -> mrun stays loose -> only extra emissions.
                if (quad == 0) atomicMin(&mrun[tok], __builtin_bit_cast(unsigned, vm));
            }
        }
    }
    __syncthreads();   // list/cnt final; Bs free for overlay

    // ---- exact fp32 rescore of candidates (best64 overlays Bs) ----
    unsigned long long* best64 = (unsigned long long*)&Bs[0][0];
    if (tid < BM) best64[tid] = ~0ULL;
    __syncthreads();

    int n = cnt; if (n > CAP) n = CAP;
    for (int p = wave; p < n; p += 8) {
        unsigned e = list[p];
        int tok = (int)(e >> 13), code = (int)(e & 8191);
        float4 hv = *(const float4*)(h + (size_t)(tokBase + tok) * DIMS + lane * 4);
        float4 cv = *(const float4*)(cb + (size_t)code * DIMS + lane * 4);
        float d = hv.x * cv.x + hv.y * cv.y + hv.z * cv.z + hv.w * cv.w;
#pragma unroll
        for (int m = 1; m < 64; m <<= 1) d += __shfl_xor(d, m);
        float s = c2g[code] - 2.f * d;
        if (lane == 0)
            atomicMin(&best64[tok], ((unsigned long long)fenc(s) << 32) | (unsigned)code);
    }
    __syncthreads();

    if (tid < BM)
        out_idx[tokBase + tid] = (float)(unsigned)(best64[tid] & 0xFFFFFFFFULL);
#pragma unroll
    for (int e = tid; e < BM * (DIMS / 4); e += 512) {
        int r = e >> 6, c4 = e & 63;
        int idx = (int)(unsigned)(best64[r] & 0xFFFFFFFFULL);
        float4 v = *(const float4*)(cb + (size_t)idx * DIMS + c4 * 4);
        *(float4*)(out_q + (size_t)(tokBase + r) * DIMS + c4 * 4) = v;
    }
}

extern "C" void kernel_launch(void* const* d_in, const int* in_sizes, int n_in,
                              void* d_out, int out_size, void* d_ws, size_t ws_size,
                              hipStream_t stream) {
    const float* h  = (const float*)d_in[0];   // [32768, 256]
    const float* cb = (const float*)d_in[1];   // [8192, 256]
    float* out_q   = (float*)d_out;
    float* out_idx = (float*)d_out + (size_t)NTOK * DIMS;

    float* c2 = (float*)d_ws;                                       // 32 KB
    unsigned short* cbbf = (unsigned short*)((char*)d_ws + 32768);  // 4 MB
    const size_t needed = 32768 + (size_t)KCODES * DIMS * 2;
    const int wsbf = (ws_size >= needed) ? 1 : 0;

    prep_kernel<<<KCODES / 4, 256, 0, stream>>>(cb, c2, cbbf, wsbf);
    if (wsbf)
        vq_main<true><<<NTOK / BM, 512, 0, stream>>>(h, cb, cbbf, c2, out_q, out_idx);
    else
        vq_main<false><<<NTOK / BM, 512, 0, stream>>>(h, cb, (const unsigned short*)nullptr, c2, out_q, out_idx);
}